// Round 5
// baseline (438.367 us; speedup 1.0000x reference)
//
#include <hip/hip_runtime.h>

typedef __attribute__((ext_vector_type(8))) short short8;
typedef __attribute__((ext_vector_type(4))) float f32x4;

__device__ __forceinline__ float b2f(unsigned short u) {
    unsigned int i = ((unsigned int)u) << 16;
    return __builtin_bit_cast(float, i);
}
__device__ __forceinline__ unsigned short f2b(float f) {
    unsigned int u = __builtin_bit_cast(unsigned int, f);
    unsigned int r = (u + 0x7fffu + ((u >> 16) & 1u)) >> 16;
    return (unsigned short)r;
}

// async 16B global->LDS copy; lds base must be wave-uniform (HW adds lane*16B)
__device__ __forceinline__ void async16(unsigned short* lds, const unsigned short* g) {
    __builtin_amdgcn_global_load_lds(
        (const __attribute__((address_space(1))) unsigned int*)g,
        (__attribute__((address_space(3))) unsigned int*)lds,
        16, 0, 0);
}

// XCD-aware block swizzle; only applied when gridDim.y % 8 == 0 (bijective).
__device__ __forceinline__ void xcd_swizzle(int& bx, int& by) {
    if ((gridDim.y & 7) == 0) {
        const int nx = gridDim.x;
        const int rows_per_xcd = gridDim.y >> 3;
        const int flat = blockIdx.y * nx + blockIdx.x;
        const int xcd = flat & 7;
        const int i = flat >> 3;
        by = xcd * rows_per_xcd + i / nx;
        bx = i % nx;
    } else {
        bx = blockIdx.x; by = blockIdx.y;
    }
}

// ------------- weight prep: fp32 -> bf16 transpose (+ optional row-major) -----
__global__ __launch_bounds__(256)
void wprep(const float* __restrict__ in, unsigned short* __restrict__ outT,
           unsigned short* __restrict__ rm, int R, int C) {
    __shared__ unsigned short t[32][33];
    const int r0 = blockIdx.y * 32, c0 = blockIdx.x * 32;
    const int tx = threadIdx.x & 31, ty = threadIdx.x >> 5;
    #pragma unroll
    for (int i = 0; i < 32; i += 8) {
        unsigned short v = f2b(in[(size_t)(r0 + ty + i) * C + c0 + tx]);
        t[ty + i][tx] = v;
        if (rm) rm[(size_t)(r0 + ty + i) * C + c0 + tx] = v;
    }
    __syncthreads();
    #pragma unroll
    for (int i = 0; i < 32; i += 8)
        outT[(size_t)(c0 + ty + i) * R + r0 + tx] = t[tx][ty + i];
}

// ------------- x: fused fp32->bf16 convert + transpose, 16B IO both sides -----
// in: (32768 x 768) fp32. rm: (32768 x 768) bf16. tm: (768 x 32768) bf16.
__global__ __launch_bounds__(256)
void cvt_tr64(const float* __restrict__ in, unsigned short* __restrict__ rm,
              unsigned short* __restrict__ tm) {
    __shared__ unsigned short T[64][72];
    const int c0 = blockIdx.x * 64, r0 = blockIdx.y * 64;
    const int tr = threadIdx.x >> 2, tc = (threadIdx.x & 3) * 16;
    {
        const float* src = in + (size_t)(r0 + tr) * 768 + c0 + tc;
        f32x4 a0 = *(const f32x4*)(src);
        f32x4 a1 = *(const f32x4*)(src + 4);
        f32x4 a2 = *(const f32x4*)(src + 8);
        f32x4 a3 = *(const f32x4*)(src + 12);
        short8 o0, o1;
        #pragma unroll
        for (int j = 0; j < 4; ++j) {
            o0[j] = (short)f2b(a0[j]); o0[j + 4] = (short)f2b(a1[j]);
            o1[j] = (short)f2b(a2[j]); o1[j + 4] = (short)f2b(a3[j]);
        }
        *(short8*)&T[tr][tc] = o0;
        *(short8*)&T[tr][tc + 8] = o1;
        unsigned short* d = rm + (size_t)(r0 + tr) * 768 + c0 + tc;
        *(short8*)(d) = o0;
        *(short8*)(d + 8) = o1;
    }
    __syncthreads();
    short8 s0, s1;
    #pragma unroll
    for (int e = 0; e < 8; ++e) {
        s0[e] = (short)T[tc + e][tr];
        s1[e] = (short)T[tc + 8 + e][tr];
    }
    unsigned short* d = tm + (size_t)(c0 + tr) * 32768 + r0 + tc;
    *(short8*)(d) = s0;
    *(short8*)(d + 8) = s1;
}

// tile index t in [0,21) -> (r,c) with r <= c over a 6x6 upper triangle
__device__ __forceinline__ void tri_rc(int t, int& r, int& c) {
    r = 0;
    int rem = t;
    while (rem >= 6 - r) { rem -= 6 - r; ++r; }
    c = r + rem;
}

// =============================================================================
// Symmetric split-K Gram partials: only upper-triangular 128x128 tiles.
// Grid (21, 64): blockIdx.x = tile, blockIdx.y = b*8 + s (K-split S=8, 512 tok).
// Gp[(z*21 + t)*16384] bf16, m97 structure, BK=32.
// =============================================================================
__global__ __launch_bounds__(256, 4)
void gram_split_sym(const unsigned short* __restrict__ xT, unsigned short* __restrict__ Gp) {
    __shared__ unsigned short As[128 * 32];
    __shared__ unsigned short Bs[128 * 32];
    const int z = blockIdx.y, b = z >> 3, s = z & 7;
    int tr_, tc_;
    tri_rc(blockIdx.x, tr_, tc_);
    const int tid  = threadIdx.x;
    const int wave = tid >> 6, lane = tid & 63;
    const int quad = lane >> 4, m16 = lane & 15;
    const int bm = tr_ * 128, bn = tc_ * 128;
    const int wm = (wave >> 1) * 64, wn = (wave & 1) * 64;
    const int srow = wave * 32 + (lane >> 2);
    const int scol = (lane & 3) * 8;
    const unsigned short* base = xT + (size_t)b * 4096 + s * 512 + scol;
    const unsigned short* Ag = base + (size_t)(bm + srow) * 32768;
    const unsigned short* Bg = base + (size_t)(bn + srow) * 32768;
    unsigned short* Asw = &As[(wave * 32) * 32];
    unsigned short* Bsw = &Bs[(wave * 32) * 32];
    f32x4 acc[4][4] = {};

    for (int k0 = 0; k0 < 512; k0 += 32) {
        __syncthreads();
        async16(Asw,           Ag + k0);
        async16(Asw + 16 * 32, Ag + k0 + (size_t)16 * 32768);
        async16(Bsw,           Bg + k0);
        async16(Bsw + 16 * 32, Bg + k0 + (size_t)16 * 32768);
        __syncthreads();
        short8 af[4], bfr[4];
        #pragma unroll
        for (int i = 0; i < 4; ++i)
            af[i] = *(const short8*)&As[(wm + i * 16 + m16) * 32 + quad * 8];
        #pragma unroll
        for (int j = 0; j < 4; ++j)
            bfr[j] = *(const short8*)&Bs[(wn + j * 16 + m16) * 32 + quad * 8];
        #pragma unroll
        for (int i = 0; i < 4; ++i)
            #pragma unroll
            for (int j = 0; j < 4; ++j)
                acc[i][j] = __builtin_amdgcn_mfma_f32_16x16x32_bf16(af[i], bfr[j], acc[i][j], 0, 0, 0);
    }
    unsigned short* C = Gp + ((size_t)z * 21 + blockIdx.x) * 16384;
    #pragma unroll
    for (int j = 0; j < 4; ++j) {
        const int col = wn + j * 16 + m16;
        #pragma unroll
        for (int i = 0; i < 4; ++i)
            #pragma unroll
            for (int r = 0; r < 4; ++r) {
                const int row = wm + i * 16 + quad * 4 + r;
                C[row * 128 + col] = f2b(acc[i][j][r]);
            }
    }
}

// ---- G[b] tile (r,c) = sum_s Gp; writes (r,c) and mirrored (c,r) -------------
__global__ __launch_bounds__(256)
void g_reduce_sym(const unsigned short* __restrict__ Gp, unsigned short* __restrict__ G) {
    const int t = blockIdx.x, b = blockIdx.y;
    int r, c;
    tri_rc(t, r, c);
    __shared__ unsigned short T[128][136];
    const int tid = threadIdx.x;
    const int row = tid >> 1, colbase = (tid & 1) * 64;
    unsigned short* Gb = G + (size_t)b * 589824;
    const unsigned short* p0 = Gp + ((size_t)(b * 8) * 21 + t) * 16384 + row * 128;
    #pragma unroll
    for (int k = 0; k < 8; ++k) {
        const int col = colbase + k * 8;
        float sum[8] = {};
        #pragma unroll
        for (int s = 0; s < 8; ++s) {
            short8 v = *(const short8*)(p0 + (size_t)s * 21 * 16384 + col);
            #pragma unroll
            for (int e = 0; e < 8; ++e) sum[e] += b2f((unsigned short)v[e]);
        }
        short8 o;
        #pragma unroll
        for (int e = 0; e < 8; ++e) o[e] = (short)f2b(sum[e]);
        *(short8*)&Gb[(size_t)(r * 128 + row) * 768 + c * 128 + col] = o;
        *(short8*)&T[row][col] = o;
    }
    if (r != c) {
        __syncthreads();
        #pragma unroll
        for (int k = 0; k < 8; ++k) {
            const int col = colbase + k * 8;
            short8 m;
            #pragma unroll
            for (int e = 0; e < 8; ++e) m[e] = (short)T[col + e][row];
            *(short8*)&Gb[(size_t)(c * 128 + row) * 768 + r * 128 + col] = m;
        }
    }
}

// =============================================================================
// Generalized m97-style GEMM: C = A @ BT^T (bf16 in), 128x128 tile, BK=32,
// batched over blockIdx.z. OM: 0 = bf16 out, 2 = f32 out + bias[col].
// =============================================================================
template<int OM>
__global__ __launch_bounds__(256, 4)
void gemm_bt_g(const unsigned short* A, const unsigned short* BT,
               void* __restrict__ Cv, const float* __restrict__ bias,
               int K, int lda, int ldb, int ldc,
               long long sA, long long sB, long long sC) {
    __shared__ unsigned short As[128 * 32];
    __shared__ unsigned short Bs[128 * 32];
    const int z = blockIdx.z;
    A  += (size_t)z * sA;
    BT += (size_t)z * sB;
    int bxi, byi;
    xcd_swizzle(bxi, byi);
    const int tid  = threadIdx.x;
    const int wave = tid >> 6, lane = tid & 63;
    const int quad = lane >> 4, m16 = lane & 15;
    const int bm = byi * 128, bn = bxi * 128;
    const int wm = (wave >> 1) * 64, wn = (wave & 1) * 64;
    const int srow = wave * 32 + (lane >> 2);
    const int scol = (lane & 3) * 8;
    const unsigned short* Ag = A + (size_t)(bm + srow) * lda + scol;
    const unsigned short* Bg = BT + (size_t)(bn + srow) * ldb + scol;
    unsigned short* Asw = &As[(wave * 32) * 32];
    unsigned short* Bsw = &Bs[(wave * 32) * 32];
    f32x4 acc[4][4] = {};

    for (int k0 = 0; k0 < K; k0 += 32) {
        __syncthreads();
        async16(Asw,           Ag + k0);
        async16(Asw + 16 * 32, Ag + k0 + (size_t)16 * lda);
        async16(Bsw,           Bg + k0);
        async16(Bsw + 16 * 32, Bg + k0 + (size_t)16 * ldb);
        __syncthreads();
        short8 af[4], bfr[4];
        #pragma unroll
        for (int i = 0; i < 4; ++i)
            af[i] = *(const short8*)&As[(wm + i * 16 + m16) * 32 + quad * 8];
        #pragma unroll
        for (int j = 0; j < 4; ++j)
            bfr[j] = *(const short8*)&Bs[(wn + j * 16 + m16) * 32 + quad * 8];
        #pragma unroll
        for (int i = 0; i < 4; ++i)
            #pragma unroll
            for (int j = 0; j < 4; ++j)
                acc[i][j] = __builtin_amdgcn_mfma_f32_16x16x32_bf16(af[i], bfr[j], acc[i][j], 0, 0, 0);
    }

    if constexpr (OM == 0) {
        unsigned short* C = (unsigned short*)Cv + (size_t)z * sC;
        #pragma unroll
        for (int j = 0; j < 4; ++j) {
            const int col = bn + wn + j * 16 + m16;
            #pragma unroll
            for (int i = 0; i < 4; ++i)
                #pragma unroll
                for (int r = 0; r < 4; ++r) {
                    const int row = bm + wm + i * 16 + quad * 4 + r;
                    C[(size_t)row * ldc + col] = f2b(acc[i][j][r]);
                }
        }
    } else {
        float* C = (float*)Cv + (size_t)z * sC;
        #pragma unroll
        for (int j = 0; j < 4; ++j) {
            const int col = bn + wn + j * 16 + m16;
            const float bv = bias[col];
            #pragma unroll
            for (int i = 0; i < 4; ++i)
                #pragma unroll
                for (int r = 0; r < 4; ++r) {
                    const int row = bm + wm + i * 16 + quad * 4 + r;
                    C[(size_t)row * ldc + col] = acc[i][j][r] + bv;
                }
        }
    }
}

// ---- qn2/kn2 = rowwise dot of WqkvT[j,:] and TQKT_b[j,:], j in [0,1536) ------
__global__ __launch_bounds__(256)
void rownorm(const unsigned short* __restrict__ W, const unsigned short* __restrict__ T,
             float* __restrict__ qn2, float* __restrict__ kn2) {
    const int row = blockIdx.x * 4 + (threadIdx.x >> 6);   // 0..12287
    const int lane = threadIdx.x & 63;
    const int b = row / 1536, j = row % 1536;
    const unsigned short* wr = W + (size_t)j * 768;
    const unsigned short* tr = T + (size_t)b * 1179648 + (size_t)j * 768;
    float s = 0.f;
    {
        short8 a = *(const short8*)(wr + lane * 8);
        short8 c = *(const short8*)(tr + lane * 8);
        #pragma unroll
        for (int e = 0; e < 8; ++e) s += b2f((unsigned short)a[e]) * b2f((unsigned short)c[e]);
    }
    if (lane < 32) {
        short8 a = *(const short8*)(wr + 512 + lane * 8);
        short8 c = *(const short8*)(tr + 512 + lane * 8);
        #pragma unroll
        for (int e = 0; e < 8; ++e) s += b2f((unsigned short)a[e]) * b2f((unsigned short)c[e]);
    }
    #pragma unroll
    for (int o = 32; o; o >>= 1) s += __shfl_down(s, o);
    if (lane == 0) {
        if (j < 768) qn2[b * 768 + j] = s;
        else         kn2[b * 768 + j - 768] = s;
    }
}

// =============================================================================
// Fused per-(b,h): S = Wk_h^T (G Wq_h) via MFMA, softmax over q, then
// W2_h = Wv_h @ attn_h (768x64). Grid 96 blocks x 256 threads.
// =============================================================================
__global__ __launch_bounds__(256)
void head_fused(const unsigned short* __restrict__ WqkvT,
                const unsigned short* __restrict__ TQKT,
                const unsigned short* __restrict__ Wbf,
                const float* __restrict__ qn2, const float* __restrict__ kn2,
                const float* __restrict__ temp, unsigned short* __restrict__ W2) {
    const int bh = blockIdx.x, b = bh / 12, h = bh % 12;
    __shared__ unsigned short As[64][72], Bs[64][72], At[64][72];
    __shared__ float Sf[64][65];
    __shared__ float qinv[64], kinv[64], red[64][4], red2[64][4];
    const int tid = threadIdx.x;
    const int wave = tid >> 6, lane = tid & 63;
    const int quad = lane >> 4, m16 = lane & 15;
    const int wr = wave >> 1, wc = wave & 1;

    if (tid < 64) {
        qinv[tid] = 1.0f / fmaxf(sqrtf(qn2[b * 768 + h * 64 + tid]), 1e-12f);
        kinv[tid] = 1.0f / fmaxf(sqrtf(kn2[b * 768 + h * 64 + tid]), 1e-12f);
    }

    // ---- phase A: S (64x64) = A . B^T, A rows = Wk cols, B rows = (G Wq)^T ---
    f32x4 sacc[2][2] = {};
    const int srow = tid >> 3, scol8 = (tid & 7) * 8;
    const unsigned short* Arow = WqkvT + (size_t)(768 + h * 64) * 768;
    const unsigned short* Brow = TQKT + (size_t)(b * 1536 + h * 64) * 768;
    for (int k0 = 0; k0 < 768; k0 += 64) {
        __syncthreads();
        *(short8*)&As[srow][scol8]      = *(const short8*)(Arow + (size_t)srow * 768 + k0 + scol8);
        *(short8*)&As[srow + 32][scol8] = *(const short8*)(Arow + (size_t)(srow + 32) * 768 + k0 + scol8);
        *(short8*)&Bs[srow][scol8]      = *(const short8*)(Brow + (size_t)srow * 768 + k0 + scol8);
        *(short8*)&Bs[srow + 32][scol8] = *(const short8*)(Brow + (size_t)(srow + 32) * 768 + k0 + scol8);
        __syncthreads();
        #pragma unroll
        for (int ks = 0; ks < 2; ++ks) {
            short8 af[2], bv[2];
            af[0] = *(const short8*)&As[wr * 32 + m16][ks * 32 + quad * 8];
            af[1] = *(const short8*)&As[wr * 32 + 16 + m16][ks * 32 + quad * 8];
            bv[0] = *(const short8*)&Bs[wc * 32 + m16][ks * 32 + quad * 8];
            bv[1] = *(const short8*)&Bs[wc * 32 + 16 + m16][ks * 32 + quad * 8];
            #pragma unroll
            for (int i = 0; i < 2; ++i)
                #pragma unroll
                for (int j = 0; j < 2; ++j)
                    sacc[i][j] = __builtin_amdgcn_mfma_f32_16x16x32_bf16(af[i], bv[j], sacc[i][j], 0, 0, 0);
        }
    }
    __syncthreads();
    #pragma unroll
    for (int i = 0; i < 2; ++i)
        #pragma unroll
        for (int j = 0; j < 2; ++j)
            #pragma unroll
            for (int r = 0; r < 4; ++r)
                Sf[wr * 32 + i * 16 + quad * 4 + r][wc * 32 + j * 16 + m16] = sacc[i][j][r];
    __syncthreads();

    // ---- phase B: softmax over q for each row p (4 lane-groups of 16 q) ------
    const float tt = temp[h];
    const int p = tid & 63, g = tid >> 6;
    float l[16], mx = -1e30f;
    const float kvp = tt * kinv[p];
    #pragma unroll
    for (int e = 0; e < 16; ++e) {
        l[e] = kvp * Sf[p][g * 16 + e] * qinv[g * 16 + e];
        mx = fmaxf(mx, l[e]);
    }
    red[p][g] = mx;
    __syncthreads();
    mx = fmaxf(fmaxf(red[p][0], red[p][1]), fmaxf(red[p][2], red[p][3]));
    float sum = 0.f;
    #pragma unroll
    for (int e = 0; e < 16; ++e) { l[e] = __expf(l[e] - mx); sum += l[e]; }
    red2[p][g] = sum;
    __syncthreads();
    sum = red2[p][0] + red2[p][1] + red2[p][2] + red2[p][3];
    const float inv = 1.0f / sum;
    #pragma unroll
    for (int e = 0; e < 16; ++e) At[g * 16 + e][p] = f2b(l[e] * inv);
    __syncthreads();

    // ---- phase C: W2_h (768x64) = Wv_h @ attn; A frags direct from global ----
    const unsigned short* Wv = Wbf + 1536 + h * 64;
    unsigned short* W2b = W2 + (size_t)b * 589824 + h * 64;
    #pragma unroll
    for (int pass = 0; pass < 3; ++pass) {
        const int rb = wave * 192 + pass * 64;
        f32x4 wacc[4][4] = {};
        #pragma unroll
        for (int ks = 0; ks < 2; ++ks) {
            short8 av[4], bv[4];
            #pragma unroll
            for (int i = 0; i < 4; ++i)
                av[i] = *(const short8*)(Wv + (size_t)(rb + i * 16 + m16) * 2304 + ks * 32 + quad * 8);
            #pragma unroll
            for (int j = 0; j < 4; ++j)
                bv[j] = *(const short8*)&At[j * 16 + m16][ks * 32 + quad * 8];
            #pragma unroll
            for (int i = 0; i < 4; ++i)
                #pragma unroll
                for (int j = 0; j < 4; ++j)
                    wacc[i][j] = __builtin_amdgcn_mfma_f32_16x16x32_bf16(av[i], bv[j], wacc[i][j], 0, 0, 0);
        }
        #pragma unroll
        for (int j = 0; j < 4; ++j)
            #pragma unroll
            for (int i = 0; i < 4; ++i)
                #pragma unroll
                for (int r = 0; r < 4; ++r)
                    W2b[(size_t)(rb + i * 16 + quad * 4 + r) * 768 + j * 16 + m16] = f2b(wacc[i][j][r]);
    }
}

extern "C" void kernel_launch(void* const* d_in, const int* in_sizes, int n_in,
                              void* d_out, int out_size, void* d_ws, size_t ws_size,
                              hipStream_t stream) {
    const float *x = nullptr, *Wqkv = nullptr, *temp = nullptr, *Wout = nullptr, *bout = nullptr;
    for (int i = 0; i < n_in; ++i) {
        switch (in_sizes[i]) {
            case 25165824: x    = (const float*)d_in[i]; break;  // 8*4096*768
            case 1769472:  Wqkv = (const float*)d_in[i]; break;  // 768*2304
            case 12:       temp = (const float*)d_in[i]; break;  // (1,12,1,1)
            case 589824:   Wout = (const float*)d_in[i]; break;  // 768*768
            case 768:      bout = (const float*)d_in[i]; break;  // (768,)
        }
    }
    float* out = (float*)d_out;  // (8,4096,768) fp32

    // ---------------- workspace layout (bytes, peak ~153 MB) ------------------
    char* ws = (char*)d_ws;
    unsigned short* WqkvT = (unsigned short*)(ws + 0);          //  3,538,944 (2304x768)
    unsigned short* WoutT = (unsigned short*)(ws + 3538944);    //  1,179,648 (768x768)
    unsigned short* Wbf   = (unsigned short*)(ws + 4718592);    //  3,538,944 (768x2304)
    unsigned short* xb    = (unsigned short*)(ws + 8257536);    // 50,331,648 (32768x768)
    unsigned short* xT    = (unsigned short*)(ws + 58589184);   // 50,331,648 (768x32768); dead after gram
    unsigned short* G     = (unsigned short*)(ws + 58589184);   //  9,437,184 (8x768x768) [aliases dead xT]
    unsigned short* TQKT  = (unsigned short*)(ws + 68026368);   // 18,874,368 (8x1536x768) [in dead xT]
    float*          qn2   = (float*)         (ws + 86900736);   //     24,576
    float*          kn2   = (float*)         (ws + 86925312);   //     24,576
    unsigned short* W2    = (unsigned short*)(ws + 86949888);   //  9,437,184 (8x768x768)
    unsigned short* FT    = (unsigned short*)(ws + 96387072);   //  9,437,184 (8x768x768)
    unsigned short* Gp    = (unsigned short*)(ws + 108920832);  // 44,040,192 (64x21x128x128 bf16)
    (void)ws_size;  // peak 152,961,024 B; >=258 MB proven available in earlier rounds

    // ---- weight prep (WqkvT + Wbf fused in one pass) -------------------------
    wprep<<<dim3(72, 24), 256, 0, stream>>>(Wqkv, WqkvT, Wbf, 768, 2304);
    wprep<<<dim3(24, 24), 256, 0, stream>>>(Wout, WoutT, nullptr, 768, 768);

    // ---- x -> bf16 row-major + transposed (vectorized both sides) ------------
    cvt_tr64<<<dim3(12, 512), 256, 0, stream>>>(x, xb, xT);

    // ---- G_b = x_b^T x_b: symmetric upper-tri tiles, split-K=8 + reduce ------
    gram_split_sym<<<dim3(21, 64), 256, 0, stream>>>(xT, Gp);
    g_reduce_sym<<<dim3(21, 8), 256, 0, stream>>>(Gp, G);

    // ---- TQKT_b = Wqk^T G_b  (1536x768, K=768) -------------------------------
    gemm_bt_g<0><<<dim3(6, 12, 8), 256, 0, stream>>>(
        WqkvT, G, TQKT, nullptr, 768, 768, 768, 768, 0LL, 589824LL, 1179648LL);

    // ---- qn2/kn2 = diag(W^T G W) ---------------------------------------------
    rownorm<<<dim3(3072), 256, 0, stream>>>(WqkvT, TQKT, qn2, kn2);

    // ---- fused: S + softmax + W2 (block-diagonal) per (b,h) ------------------
    head_fused<<<dim3(96), 256, 0, stream>>>(WqkvT, TQKT, Wbf, qn2, kn2, temp, W2);

    // ---- FT_b = (W2_b @ Wout)^T  (768x768, K=768) ----------------------------
    gemm_bt_g<0><<<dim3(6, 6, 8), 256, 0, stream>>>(
        WoutT, W2, FT, nullptr, 768, 768, 768, 768, 0LL, 589824LL, 589824LL);

    // ---- out_b = x_b @ W3_b + bout  (4096x768, K=768), f32 + bias ------------
    gemm_bt_g<2><<<dim3(6, 32, 8), 256, 0, stream>>>(
        xb, FT, out, bout, 768, 768, 768, 768, 3145728LL, 589824LL, 3145728LL);
}

// Round 6
// 393.384 us; speedup vs baseline: 1.1143x; 1.1143x over previous
//
#include <hip/hip_runtime.h>

typedef __attribute__((ext_vector_type(8))) short short8;
typedef __attribute__((ext_vector_type(4))) float f32x4;

__device__ __forceinline__ float b2f(unsigned short u) {
    unsigned int i = ((unsigned int)u) << 16;
    return __builtin_bit_cast(float, i);
}
__device__ __forceinline__ unsigned short f2b(float f) {
    unsigned int u = __builtin_bit_cast(unsigned int, f);
    unsigned int r = (u + 0x7fffu + ((u >> 16) & 1u)) >> 16;
    return (unsigned short)r;
}

// async 16B global->LDS copy; lds base must be wave-uniform (HW adds lane*16B)
__device__ __forceinline__ void async16(unsigned short* lds, const unsigned short* g) {
    __builtin_amdgcn_global_load_lds(
        (const __attribute__((address_space(1))) unsigned int*)g,
        (__attribute__((address_space(3))) unsigned int*)lds,
        16, 0, 0);
}

// XCD-aware block swizzle; only applied when gridDim.y % 8 == 0 (bijective).
__device__ __forceinline__ void xcd_swizzle(int& bx, int& by) {
    if ((gridDim.y & 7) == 0) {
        const int nx = gridDim.x;
        const int rows_per_xcd = gridDim.y >> 3;
        const int flat = blockIdx.y * nx + blockIdx.x;
        const int xcd = flat & 7;
        const int i = flat >> 3;
        by = xcd * rows_per_xcd + i / nx;
        bx = i % nx;
    } else {
        bx = blockIdx.x; by = blockIdx.y;
    }
}

// ------------- weight prep: fp32 -> bf16 transpose (+ optional row-major) -----
__global__ __launch_bounds__(256)
void wprep(const float* __restrict__ in, unsigned short* __restrict__ outT,
           unsigned short* __restrict__ rm, int R, int C) {
    __shared__ unsigned short t[32][33];
    const int r0 = blockIdx.y * 32, c0 = blockIdx.x * 32;
    const int tx = threadIdx.x & 31, ty = threadIdx.x >> 5;
    #pragma unroll
    for (int i = 0; i < 32; i += 8) {
        unsigned short v = f2b(in[(size_t)(r0 + ty + i) * C + c0 + tx]);
        t[ty + i][tx] = v;
        if (rm) rm[(size_t)(r0 + ty + i) * C + c0 + tx] = v;
    }
    __syncthreads();
    #pragma unroll
    for (int i = 0; i < 32; i += 8)
        outT[(size_t)(c0 + ty + i) * R + r0 + tx] = t[tx][ty + i];
}

// ------------- x: fused fp32->bf16 convert + transpose, 16B IO both sides -----
__global__ __launch_bounds__(256)
void cvt_tr64(const float* __restrict__ in, unsigned short* __restrict__ rm,
              unsigned short* __restrict__ tm) {
    __shared__ unsigned short T[64][72];
    const int c0 = blockIdx.x * 64, r0 = blockIdx.y * 64;
    const int tr = threadIdx.x >> 2, tc = (threadIdx.x & 3) * 16;
    {
        const float* src = in + (size_t)(r0 + tr) * 768 + c0 + tc;
        f32x4 a0 = *(const f32x4*)(src);
        f32x4 a1 = *(const f32x4*)(src + 4);
        f32x4 a2 = *(const f32x4*)(src + 8);
        f32x4 a3 = *(const f32x4*)(src + 12);
        short8 o0, o1;
        #pragma unroll
        for (int j = 0; j < 4; ++j) {
            o0[j] = (short)f2b(a0[j]); o0[j + 4] = (short)f2b(a1[j]);
            o1[j] = (short)f2b(a2[j]); o1[j + 4] = (short)f2b(a3[j]);
        }
        *(short8*)&T[tr][tc] = o0;
        *(short8*)&T[tr][tc + 8] = o1;
        unsigned short* d = rm + (size_t)(r0 + tr) * 768 + c0 + tc;
        *(short8*)(d) = o0;
        *(short8*)(d + 8) = o1;
    }
    __syncthreads();
    short8 s0, s1;
    #pragma unroll
    for (int e = 0; e < 8; ++e) {
        s0[e] = (short)T[tc + e][tr];
        s1[e] = (short)T[tc + 8 + e][tr];
    }
    unsigned short* d = tm + (size_t)(c0 + tr) * 32768 + r0 + tc;
    *(short8*)(d) = s0;
    *(short8*)(d + 8) = s1;
}

// tile index t in [0,21) -> (r,c) with r <= c over a 6x6 upper triangle
__device__ __forceinline__ void tri_rc(int t, int& r, int& c) {
    r = 0;
    int rem = t;
    while (rem >= 6 - r) { rem -= 6 - r; ++r; }
    c = r + rem;
}

// =============================================================================
// BK=64 + XOR-swizzled LDS, m97 2-barrier loop. LDS layout per operand:
// [row 128][chunk 8][8 elems], stored chunk = logical_chunk ^ (row&7).
// Staging: linear LDS dest, inverse-swizzled GLOBAL source (rule #21).
// ds_read: byte = row*128 + ((ks*4+quad)^(row&7))*16 -> conflict-free.
// =============================================================================

// ---- symmetric split-K Gram, upper-tri tiles. grid (21, 32): y = b*4 + s -----
__global__ __launch_bounds__(256, 2)
void gram64_sym(const unsigned short* __restrict__ xT, unsigned short* __restrict__ Gp) {
    __shared__ unsigned short As[128 * 64];
    __shared__ unsigned short Bs[128 * 64];
    const int z = blockIdx.y, b = z >> 2, s = z & 3;
    int tr_, tc_;
    tri_rc(blockIdx.x, tr_, tc_);
    const int tid  = threadIdx.x;
    const int wave = tid >> 6, lane = tid & 63;
    const int quad = lane >> 4, m16 = lane & 15;
    const int bm = tr_ * 128, bn = tc_ * 128;
    const int wm = (wave >> 1) * 64, wn = (wave & 1) * 64;
    const int srow = tid >> 3;                          // 0..31
    const int sc = ((tid & 7) ^ (srow & 7)) * 8;        // inverse-swizzled col
    const unsigned short* base = xT + (size_t)b * 4096 + s * 1024 + sc;
    const unsigned short* Ag = base + (size_t)(bm + srow) * 32768;
    const unsigned short* Bg = base + (size_t)(bn + srow) * 32768;
    unsigned short* Asl = As + wave * 512;
    unsigned short* Bsl = Bs + wave * 512;
    f32x4 acc[4][4] = {};

    for (int k0 = 0; k0 < 1024; k0 += 64) {
        __syncthreads();
        #pragma unroll
        for (int is = 0; is < 4; ++is) {
            async16(Asl + is * 2048, Ag + k0 + (size_t)(is * 32) * 32768);
            async16(Bsl + is * 2048, Bg + k0 + (size_t)(is * 32) * 32768);
        }
        __syncthreads();
        #pragma unroll
        for (int ks = 0; ks < 2; ++ks) {
            short8 af[4], bfr[4];
            #pragma unroll
            for (int i = 0; i < 4; ++i) {
                const int r = wm + i * 16 + m16;
                af[i] = *(const short8*)&As[r * 64 + (((ks * 4 + quad) ^ (r & 7)) << 3)];
            }
            #pragma unroll
            for (int j = 0; j < 4; ++j) {
                const int r = wn + j * 16 + m16;
                bfr[j] = *(const short8*)&Bs[r * 64 + (((ks * 4 + quad) ^ (r & 7)) << 3)];
            }
            #pragma unroll
            for (int i = 0; i < 4; ++i)
                #pragma unroll
                for (int j = 0; j < 4; ++j)
                    acc[i][j] = __builtin_amdgcn_mfma_f32_16x16x32_bf16(af[i], bfr[j], acc[i][j], 0, 0, 0);
        }
    }
    unsigned short* C = Gp + ((size_t)z * 21 + blockIdx.x) * 16384;
    #pragma unroll
    for (int j = 0; j < 4; ++j) {
        const int col = wn + j * 16 + m16;
        #pragma unroll
        for (int i = 0; i < 4; ++i)
            #pragma unroll
            for (int r = 0; r < 4; ++r) {
                const int row = wm + i * 16 + quad * 4 + r;
                C[row * 128 + col] = f2b(acc[i][j][r]);
            }
    }
}

// ---- G[b] tile (r,c) = sum_s Gp (S=4); writes (r,c) and mirror (c,r) ---------
__global__ __launch_bounds__(256)
void g_reduce_sym(const unsigned short* __restrict__ Gp, unsigned short* __restrict__ G) {
    const int t = blockIdx.x, b = blockIdx.y;
    int r, c;
    tri_rc(t, r, c);
    __shared__ unsigned short T[128][136];
    const int tid = threadIdx.x;
    const int row = tid >> 1, colbase = (tid & 1) * 64;
    unsigned short* Gb = G + (size_t)b * 589824;
    const unsigned short* p0 = Gp + ((size_t)(b * 4) * 21 + t) * 16384 + row * 128;
    #pragma unroll
    for (int k = 0; k < 8; ++k) {
        const int col = colbase + k * 8;
        float sum[8] = {};
        #pragma unroll
        for (int s = 0; s < 4; ++s) {
            short8 v = *(const short8*)(p0 + (size_t)s * 21 * 16384 + col);
            #pragma unroll
            for (int e = 0; e < 8; ++e) sum[e] += b2f((unsigned short)v[e]);
        }
        short8 o;
        #pragma unroll
        for (int e = 0; e < 8; ++e) o[e] = (short)f2b(sum[e]);
        *(short8*)&Gb[(size_t)(r * 128 + row) * 768 + c * 128 + col] = o;
        *(short8*)&T[row][col] = o;
    }
    if (r != c) {
        __syncthreads();
        #pragma unroll
        for (int k = 0; k < 8; ++k) {
            const int col = colbase + k * 8;
            short8 m;
            #pragma unroll
            for (int e = 0; e < 8; ++e) m[e] = (short)T[col + e][row];
            *(short8*)&Gb[(size_t)(c * 128 + row) * 768 + r * 128 + col] = m;
        }
    }
}

// ---- BK=64 swizzled generalized GEMM (used for the big final GEMM) -----------
template<int OM>
__global__ __launch_bounds__(256, 2)
void gemm_bt64(const unsigned short* A, const unsigned short* BT,
               void* __restrict__ Cv, const float* __restrict__ bias,
               int K, int lda, int ldb, int ldc,
               long long sA, long long sB, long long sC) {
    __shared__ unsigned short As[128 * 64];
    __shared__ unsigned short Bs[128 * 64];
    const int z = blockIdx.z;
    A  += (size_t)z * sA;
    BT += (size_t)z * sB;
    int bxi, byi;
    xcd_swizzle(bxi, byi);
    const int tid  = threadIdx.x;
    const int wave = tid >> 6, lane = tid & 63;
    const int quad = lane >> 4, m16 = lane & 15;
    const int bm = byi * 128, bn = bxi * 128;
    const int wm = (wave >> 1) * 64, wn = (wave & 1) * 64;
    const int srow = tid >> 3;
    const int sc = ((tid & 7) ^ (srow & 7)) * 8;
    const unsigned short* Ag = A + (size_t)(bm + srow) * lda + sc;
    const unsigned short* Bg = BT + (size_t)(bn + srow) * ldb + sc;
    unsigned short* Asl = As + wave * 512;
    unsigned short* Bsl = Bs + wave * 512;
    f32x4 acc[4][4] = {};

    for (int k0 = 0; k0 < K; k0 += 64) {
        __syncthreads();
        #pragma unroll
        for (int is = 0; is < 4; ++is) {
            async16(Asl + is * 2048, Ag + k0 + (size_t)(is * 32) * lda);
            async16(Bsl + is * 2048, Bg + k0 + (size_t)(is * 32) * ldb);
        }
        __syncthreads();
        #pragma unroll
        for (int ks = 0; ks < 2; ++ks) {
            short8 af[4], bfr[4];
            #pragma unroll
            for (int i = 0; i < 4; ++i) {
                const int r = wm + i * 16 + m16;
                af[i] = *(const short8*)&As[r * 64 + (((ks * 4 + quad) ^ (r & 7)) << 3)];
            }
            #pragma unroll
            for (int j = 0; j < 4; ++j) {
                const int r = wn + j * 16 + m16;
                bfr[j] = *(const short8*)&Bs[r * 64 + (((ks * 4 + quad) ^ (r & 7)) << 3)];
            }
            #pragma unroll
            for (int i = 0; i < 4; ++i)
                #pragma unroll
                for (int j = 0; j < 4; ++j)
                    acc[i][j] = __builtin_amdgcn_mfma_f32_16x16x32_bf16(af[i], bfr[j], acc[i][j], 0, 0, 0);
        }
    }

    if constexpr (OM == 0) {
        unsigned short* C = (unsigned short*)Cv + (size_t)z * sC;
        #pragma unroll
        for (int j = 0; j < 4; ++j) {
            const int col = bn + wn + j * 16 + m16;
            #pragma unroll
            for (int i = 0; i < 4; ++i)
                #pragma unroll
                for (int r = 0; r < 4; ++r) {
                    const int row = bm + wm + i * 16 + quad * 4 + r;
                    C[(size_t)row * ldc + col] = f2b(acc[i][j][r]);
                }
        }
    } else {
        float* C = (float*)Cv + (size_t)z * sC;
        #pragma unroll
        for (int j = 0; j < 4; ++j) {
            const int col = bn + wn + j * 16 + m16;
            const float bv = bias[col];
            #pragma unroll
            for (int i = 0; i < 4; ++i)
                #pragma unroll
                for (int r = 0; r < 4; ++r) {
                    const int row = bm + wm + i * 16 + quad * 4 + r;
                    C[(size_t)row * ldc + col] = acc[i][j][r] + bv;
                }
        }
    }
}

// ---- BK=32 m97 GEMM (small weight-chain GEMMs: TQKT, FT) ---------------------
template<int OM>
__global__ __launch_bounds__(256, 4)
void gemm_bt_g(const unsigned short* A, const unsigned short* BT,
               void* __restrict__ Cv, const float* __restrict__ bias,
               int K, int lda, int ldb, int ldc,
               long long sA, long long sB, long long sC) {
    __shared__ unsigned short As[128 * 32];
    __shared__ unsigned short Bs[128 * 32];
    const int z = blockIdx.z;
    A  += (size_t)z * sA;
    BT += (size_t)z * sB;
    int bxi, byi;
    xcd_swizzle(bxi, byi);
    const int tid  = threadIdx.x;
    const int wave = tid >> 6, lane = tid & 63;
    const int quad = lane >> 4, m16 = lane & 15;
    const int bm = byi * 128, bn = bxi * 128;
    const int wm = (wave >> 1) * 64, wn = (wave & 1) * 64;
    const int srow = wave * 32 + (lane >> 2);
    const int scol = (lane & 3) * 8;
    const unsigned short* Ag = A + (size_t)(bm + srow) * lda + scol;
    const unsigned short* Bg = BT + (size_t)(bn + srow) * ldb + scol;
    unsigned short* Asw = &As[(wave * 32) * 32];
    unsigned short* Bsw = &Bs[(wave * 32) * 32];
    f32x4 acc[4][4] = {};

    for (int k0 = 0; k0 < K; k0 += 32) {
        __syncthreads();
        async16(Asw,           Ag + k0);
        async16(Asw + 16 * 32, Ag + k0 + (size_t)16 * lda);
        async16(Bsw,           Bg + k0);
        async16(Bsw + 16 * 32, Bg + k0 + (size_t)16 * ldb);
        __syncthreads();
        short8 af[4], bfr[4];
        #pragma unroll
        for (int i = 0; i < 4; ++i)
            af[i] = *(const short8*)&As[(wm + i * 16 + m16) * 32 + quad * 8];
        #pragma unroll
        for (int j = 0; j < 4; ++j)
            bfr[j] = *(const short8*)&Bs[(wn + j * 16 + m16) * 32 + quad * 8];
        #pragma unroll
        for (int i = 0; i < 4; ++i)
            #pragma unroll
            for (int j = 0; j < 4; ++j)
                acc[i][j] = __builtin_amdgcn_mfma_f32_16x16x32_bf16(af[i], bfr[j], acc[i][j], 0, 0, 0);
    }

    if constexpr (OM == 0) {
        unsigned short* C = (unsigned short*)Cv + (size_t)z * sC;
        #pragma unroll
        for (int j = 0; j < 4; ++j) {
            const int col = bn + wn + j * 16 + m16;
            #pragma unroll
            for (int i = 0; i < 4; ++i)
                #pragma unroll
                for (int r = 0; r < 4; ++r) {
                    const int row = bm + wm + i * 16 + quad * 4 + r;
                    C[(size_t)row * ldc + col] = f2b(acc[i][j][r]);
                }
        }
    } else {
        float* C = (float*)Cv + (size_t)z * sC;
        #pragma unroll
        for (int j = 0; j < 4; ++j) {
            const int col = bn + wn + j * 16 + m16;
            const float bv = bias[col];
            #pragma unroll
            for (int i = 0; i < 4; ++i)
                #pragma unroll
                for (int r = 0; r < 4; ++r) {
                    const int row = bm + wm + i * 16 + quad * 4 + r;
                    C[(size_t)row * ldc + col] = acc[i][j][r] + bv;
                }
        }
    }
}

// ---- qn2/kn2 = rowwise dot of WqkvT[j,:] and TQKT_b[j,:], j in [0,1536) ------
__global__ __launch_bounds__(256)
void rownorm(const unsigned short* __restrict__ W, const unsigned short* __restrict__ T,
             float* __restrict__ qn2, float* __restrict__ kn2) {
    const int row = blockIdx.x * 4 + (threadIdx.x >> 6);   // 0..12287
    const int lane = threadIdx.x & 63;
    const int b = row / 1536, j = row % 1536;
    const unsigned short* wr = W + (size_t)j * 768;
    const unsigned short* tr = T + (size_t)b * 1179648 + (size_t)j * 768;
    float s = 0.f;
    {
        short8 a = *(const short8*)(wr + lane * 8);
        short8 c = *(const short8*)(tr + lane * 8);
        #pragma unroll
        for (int e = 0; e < 8; ++e) s += b2f((unsigned short)a[e]) * b2f((unsigned short)c[e]);
    }
    if (lane < 32) {
        short8 a = *(const short8*)(wr + 512 + lane * 8);
        short8 c = *(const short8*)(tr + 512 + lane * 8);
        #pragma unroll
        for (int e = 0; e < 8; ++e) s += b2f((unsigned short)a[e]) * b2f((unsigned short)c[e]);
    }
    #pragma unroll
    for (int o = 32; o; o >>= 1) s += __shfl_down(s, o);
    if (lane == 0) {
        if (j < 768) qn2[b * 768 + j] = s;
        else         kn2[b * 768 + j - 768] = s;
    }
}

// =============================================================================
// Fused per-(b,h): S = Wk_h^T (G Wq_h), softmax, then 1/3 of W2_h = Wv_h@attn.
// Grid (96, 3): blockIdx.y picks the 256-row pass of phase C (A/B redundant).
// =============================================================================
__global__ __launch_bounds__(256)
void head_fused(const unsigned short* __restrict__ WqkvT,
                const unsigned short* __restrict__ TQKT,
                const unsigned short* __restrict__ Wbf,
                const float* __restrict__ qn2, const float* __restrict__ kn2,
                const float* __restrict__ temp, unsigned short* __restrict__ W2) {
    const int bh = blockIdx.x, b = bh / 12, h = bh % 12;
    __shared__ unsigned short As[64][72], Bs[64][72], At[64][72];
    __shared__ float Sf[64][65];
    __shared__ float qinv[64], kinv[64], red[64][4], red2[64][4];
    const int tid = threadIdx.x;
    const int wave = tid >> 6, lane = tid & 63;
    const int quad = lane >> 4, m16 = lane & 15;
    const int wr = wave >> 1, wc = wave & 1;

    if (tid < 64) {
        qinv[tid] = 1.0f / fmaxf(sqrtf(qn2[b * 768 + h * 64 + tid]), 1e-12f);
        kinv[tid] = 1.0f / fmaxf(sqrtf(kn2[b * 768 + h * 64 + tid]), 1e-12f);
    }

    // ---- phase A: S (64x64) = Wk_h^T . (G Wq_h) ------------------------------
    f32x4 sacc[2][2] = {};
    const int srow = tid >> 3, scol8 = (tid & 7) * 8;
    const unsigned short* Arow = WqkvT + (size_t)(768 + h * 64) * 768;
    const unsigned short* Brow = TQKT + (size_t)(b * 1536 + h * 64) * 768;
    for (int k0 = 0; k0 < 768; k0 += 64) {
        __syncthreads();
        *(short8*)&As[srow][scol8]      = *(const short8*)(Arow + (size_t)srow * 768 + k0 + scol8);
        *(short8*)&As[srow + 32][scol8] = *(const short8*)(Arow + (size_t)(srow + 32) * 768 + k0 + scol8);
        *(short8*)&Bs[srow][scol8]      = *(const short8*)(Brow + (size_t)srow * 768 + k0 + scol8);
        *(short8*)&Bs[srow + 32][scol8] = *(const short8*)(Brow + (size_t)(srow + 32) * 768 + k0 + scol8);
        __syncthreads();
        #pragma unroll
        for (int ks = 0; ks < 2; ++ks) {
            short8 af[2], bv[2];
            af[0] = *(const short8*)&As[wr * 32 + m16][ks * 32 + quad * 8];
            af[1] = *(const short8*)&As[wr * 32 + 16 + m16][ks * 32 + quad * 8];
            bv[0] = *(const short8*)&Bs[wc * 32 + m16][ks * 32 + quad * 8];
            bv[1] = *(const short8*)&Bs[wc * 32 + 16 + m16][ks * 32 + quad * 8];
            #pragma unroll
            for (int i = 0; i < 2; ++i)
                #pragma unroll
                for (int j = 0; j < 2; ++j)
                    sacc[i][j] = __builtin_amdgcn_mfma_f32_16x16x32_bf16(af[i], bv[j], sacc[i][j], 0, 0, 0);
        }
    }
    __syncthreads();
    #pragma unroll
    for (int i = 0; i < 2; ++i)
        #pragma unroll
        for (int j = 0; j < 2; ++j)
            #pragma unroll
            for (int r = 0; r < 4; ++r)
                Sf[wr * 32 + i * 16 + quad * 4 + r][wc * 32 + j * 16 + m16] = sacc[i][j][r];
    __syncthreads();

    // ---- phase B: softmax over q (4 lane-groups of 16 q per row p) -----------
    const float tt = temp[h];
    const int p = tid & 63, g = tid >> 6;
    float l[16], mx = -1e30f;
    const float kvp = tt * kinv[p];
    #pragma unroll
    for (int e = 0; e < 16; ++e) {
        l[e] = kvp * Sf[p][g * 16 + e] * qinv[g * 16 + e];
        mx = fmaxf(mx, l[e]);
    }
    red[p][g] = mx;
    __syncthreads();
    mx = fmaxf(fmaxf(red[p][0], red[p][1]), fmaxf(red[p][2], red[p][3]));
    float sum = 0.f;
    #pragma unroll
    for (int e = 0; e < 16; ++e) { l[e] = __expf(l[e] - mx); sum += l[e]; }
    red2[p][g] = sum;
    __syncthreads();
    sum = red2[p][0] + red2[p][1] + red2[p][2] + red2[p][3];
    const float inv = 1.0f / sum;
    #pragma unroll
    for (int e = 0; e < 16; ++e) At[g * 16 + e][p] = f2b(l[e] * inv);
    __syncthreads();

    // ---- phase C: one 256-row pass of W2_h = Wv_h @ attn ---------------------
    const int pass = blockIdx.y;   // 0..2
    const unsigned short* Wv = Wbf + 1536 + h * 64;
    unsigned short* W2b = W2 + (size_t)b * 589824 + h * 64;
    {
        const int rb = wave * 192 + pass * 64;
        f32x4 wacc[4][4] = {};
        #pragma unroll
        for (int ks = 0; ks < 2; ++ks) {
            short8 av[4], bv[4];
            #pragma unroll
            for (int i = 0; i < 4; ++i)
                av[i] = *(const short8*)(Wv + (size_t)(rb + i * 16 + m16) * 2304 + ks * 32 + quad * 8);
            #pragma unroll
            for (int j = 0; j < 4; ++j)
                bv[j] = *(const short8*)&At[j * 16 + m16][ks * 32 + quad * 8];
            #pragma unroll
            for (int i = 0; i < 4; ++i)
                #pragma unroll
                for (int j = 0; j < 4; ++j)
                    wacc[i][j] = __builtin_amdgcn_mfma_f32_16x16x32_bf16(av[i], bv[j], wacc[i][j], 0, 0, 0);
        }
        #pragma unroll
        for (int j = 0; j < 4; ++j)
            #pragma unroll
            for (int i = 0; i < 4; ++i)
                #pragma unroll
                for (int r = 0; r < 4; ++r)
                    W2b[(size_t)(rb + i * 16 + quad * 4 + r) * 768 + j * 16 + m16] = f2b(wacc[i][j][r]);
    }
}

extern "C" void kernel_launch(void* const* d_in, const int* in_sizes, int n_in,
                              void* d_out, int out_size, void* d_ws, size_t ws_size,
                              hipStream_t stream) {
    const float *x = nullptr, *Wqkv = nullptr, *temp = nullptr, *Wout = nullptr, *bout = nullptr;
    for (int i = 0; i < n_in; ++i) {
        switch (in_sizes[i]) {
            case 25165824: x    = (const float*)d_in[i]; break;  // 8*4096*768
            case 1769472:  Wqkv = (const float*)d_in[i]; break;  // 768*2304
            case 12:       temp = (const float*)d_in[i]; break;  // (1,12,1,1)
            case 589824:   Wout = (const float*)d_in[i]; break;  // 768*768
            case 768:      bout = (const float*)d_in[i]; break;  // (768,)
        }
    }
    float* out = (float*)d_out;  // (8,4096,768) fp32

    // ---------------- workspace layout (bytes) --------------------------------
    char* ws = (char*)d_ws;
    unsigned short* WqkvT = (unsigned short*)(ws + 0);          //  3,538,944 (2304x768)
    unsigned short* WoutT = (unsigned short*)(ws + 3538944);    //  1,179,648 (768x768)
    unsigned short* Wbf   = (unsigned short*)(ws + 4718592);    //  3,538,944 (768x2304)
    unsigned short* xb    = (unsigned short*)(ws + 8257536);    // 50,331,648 (32768x768)
    unsigned short* xT    = (unsigned short*)(ws + 58589184);   // 50,331,648 (768x32768); dead after gram
    unsigned short* G     = (unsigned short*)(ws + 58589184);   //  9,437,184 (8x768x768) [aliases dead xT]
    unsigned short* TQKT  = (unsigned short*)(ws + 68026368);   // 18,874,368 (8x1536x768) [in dead xT]
    float*          qn2   = (float*)         (ws + 86900736);   //     24,576
    float*          kn2   = (float*)         (ws + 86925312);   //     24,576
    unsigned short* W2    = (unsigned short*)(ws + 86949888);   //  9,437,184 (8x768x768)
    unsigned short* FT    = (unsigned short*)(ws + 96387072);   //  9,437,184 (8x768x768)
    unsigned short* Gp    = (unsigned short*)(ws + 108920832);  // 22,020,096 (32x21x128x128 bf16)
    (void)ws_size;  // peak ~131 MB; >=258 MB proven available in earlier rounds

    // ---- weight prep (WqkvT + Wbf fused in one pass) -------------------------
    wprep<<<dim3(72, 24), 256, 0, stream>>>(Wqkv, WqkvT, Wbf, 768, 2304);
    wprep<<<dim3(24, 24), 256, 0, stream>>>(Wout, WoutT, nullptr, 768, 768);

    // ---- x -> bf16 row-major + transposed (vectorized both sides) ------------
    cvt_tr64<<<dim3(12, 512), 256, 0, stream>>>(x, xb, xT);

    // ---- G_b = x_b^T x_b: symmetric tiles, split-K=4, BK=64 swizzled ---------
    gram64_sym<<<dim3(21, 32), 256, 0, stream>>>(xT, Gp);
    g_reduce_sym<<<dim3(21, 8), 256, 0, stream>>>(Gp, G);

    // ---- TQKT_b = Wqk^T G_b  (1536x768, K=768) -------------------------------
    gemm_bt_g<0><<<dim3(6, 12, 8), 256, 0, stream>>>(
        WqkvT, G, TQKT, nullptr, 768, 768, 768, 768, 0LL, 589824LL, 1179648LL);

    // ---- qn2/kn2 = diag(W^T G W) ---------------------------------------------
    rownorm<<<dim3(3072), 256, 0, stream>>>(WqkvT, TQKT, qn2, kn2);

    // ---- fused: S + softmax + W2 (block-diagonal), 3-way split phase C -------
    head_fused<<<dim3(96, 3), 256, 0, stream>>>(WqkvT, TQKT, Wbf, qn2, kn2, temp, W2);

    // ---- FT_b = (W2_b @ Wout)^T  (768x768, K=768) ----------------------------
    gemm_bt_g<0><<<dim3(6, 6, 8), 256, 0, stream>>>(
        WoutT, W2, FT, nullptr, 768, 768, 768, 768, 0LL, 589824LL, 589824LL);

    // ---- out_b = x_b @ W3_b + bout  (4096x768, K=768), BK=64 swizzled --------
    gemm_bt64<2><<<dim3(6, 32, 8), 256, 0, stream>>>(
        xb, FT, out, bout, 768, 768, 768, 768, 3145728LL, 589824LL, 3145728LL);
}